// Round 4
// baseline (371.249 us; speedup 1.0000x reference)
//
#include <hip/hip_runtime.h>
#include <math.h>

// Problem constants (B=4, H=16, S=4096, D=64)
#define BH 64
#define SEQ 4096
#define DIM 64
#define CHUNK 32
#define NCHUNK (SEQ / CHUNK)               // 128
#define TPB 512
#define WPB 8                              // waves per block
#define BLOCKS 256                         // 256 blocks x 8 waves = 2048 waves
#define TOTAL_WAVES (BLOCKS * WPB)
#define CPW ((BH * NCHUNK) / TOTAL_WAVES)  // 4 chunks per wave
#define PFX_SEG (NCHUNK / WPB)             // 16 chunks per wave in prefix phase

__device__ __forceinline__ float fast_rcp(float x)  { return __builtin_amdgcn_rcpf(x); }
__device__ __forceinline__ float fast_rsqrt(float x){ return __builtin_amdgcn_rsqf(x); }
__device__ __forceinline__ float fast_sigmoid(float x) {
    return fast_rcp(1.0f + __expf(-x));
}

// Manual grid barrier: device-scope atomics (m20: atomicAdd on global is
// device-scope). Atomic-RMW spin => reads bypass stale L1/L2; threadfence on
// both sides for cross-XCD release/acquire. Counters zeroed per launch by a
// hipMemsetAsync captured in the graph. Safe because the 256-block grid has
// 2x co-residency slack under __launch_bounds__(512,4) (VGPR<=128 => 2 blk/CU).
__device__ __forceinline__ void grid_barrier(int* cnt, int* flag) {
    __syncthreads();
    __threadfence();                       // release this block's writes
    if (threadIdx.x == 0) {
        int prev = atomicAdd(cnt, 1);
        if (prev == BLOCKS - 1) {
            atomicExch(flag, 1);
        } else {
            while (atomicAdd(flag, 0) == 0) {
                __builtin_amdgcn_s_sleep(8);
            }
        }
    }
    __syncthreads();
    __threadfence();                       // acquire side: invalidate caches
}

// Lane layout: lane = g*16 + h.
//   g = lane>>4 : row-slot (4 rows in flight per wave)
//   h = lane&15 : d-quad; lane holds d = h*4 + {0..3} as float4.
// Phase 1: V-only chunk sums -> P.   Phase 2: per-bh exclusive prefix of P.
// Phase 3: scan; r = ||Q||+||K||+1 computed inline (R array eliminated).
__global__ __launch_bounds__(TPB, 4) void k_fused(const float* __restrict__ Q,
                                                  const float* __restrict__ K,
                                                  const float* __restrict__ V,
                                                  float* __restrict__ P,
                                                  float* __restrict__ O,
                                                  int* __restrict__ bar) {
    __shared__ float seg[WPB][DIM];

    const int wave = threadIdx.x >> 6;
    const int lane = threadIdx.x & 63;
    const int g    = lane >> 4;
    const int h    = lane & 15;
    const int wid  = blockIdx.x * WPB + wave;

    // ---------------- Phase 1: per-chunk swiglu sums (V only) ----------------
    for (int t = 0; t < CPW; ++t) {
        const int chunk = wid * CPW + t;
        const float4* v4 = (const float4*)(V + (size_t)chunk * (CHUNK * DIM));

        float acc0 = 0.f, acc1 = 0.f, acc2 = 0.f, acc3 = 0.f;
#pragma unroll
        for (int j0 = 0; j0 < CHUNK; j0 += 4) {
            float4 v = v4[(j0 + g) * 16 + h];
            acc0 += v.x * v.x * fast_sigmoid(v.x);
            acc1 += v.y * v.y * fast_sigmoid(v.y);
            acc2 += v.z * v.z * fast_sigmoid(v.z);
            acc3 += v.w * v.w * fast_sigmoid(v.w);
        }
#pragma unroll
        for (int m = 16; m < 64; m <<= 1) {
            acc0 += __shfl_xor(acc0, m);
            acc1 += __shfl_xor(acc1, m);
            acc2 += __shfl_xor(acc2, m);
            acc3 += __shfl_xor(acc3, m);
        }
        if (g == 0) {
            float4 out = {acc0, acc1, acc2, acc3};
            ((float4*)(P + (size_t)chunk * DIM))[h] = out;
        }
    }

    grid_barrier(bar + 0, bar + 1);

    // ---------------- Phase 2: exclusive prefix over chunks per bh -----------
    if (blockIdx.x < BH) {
        const int bh = blockIdx.x;
        float* p = P + (size_t)bh * (NCHUNK * DIM) + (size_t)wave * PFX_SEG * DIM + lane;

        float tr[PFX_SEG];
#pragma unroll
        for (int i = 0; i < PFX_SEG; ++i) tr[i] = p[i * DIM];

        float run = 0.f;
#pragma unroll
        for (int i = 0; i < PFX_SEG; ++i) { float x = tr[i]; tr[i] = run; run += x; }

        seg[wave][lane] = run;
        __syncthreads();

        float carry = 0.f;
#pragma unroll
        for (int w = 0; w < WPB; ++w)
            if (w < wave) carry += seg[w][lane];

#pragma unroll
        for (int i = 0; i < PFX_SEG; ++i) p[i * DIM] = tr[i] + carry;
    }

    grid_barrier(bar + 2, bar + 3);

    // ---------------- Phase 3: sequential scan, r inline ---------------------
    const int up16 = (lane + 48) & 63;   // lane-16 with wrap (masked for g<1)
    const int up32 = (lane + 32) & 63;   // lane-32 with wrap (masked for g<2)
    const int src3 = 48 + h;             // group-3 lane with same h

    for (int t = 0; t < CPW; ++t) {
        const int chunk = wid * CPW + t;
        const size_t cbase = (size_t)chunk * (CHUNK * DIM);
        const float4* q4 = (const float4*)(Q + cbase);
        const float4* k4 = (const float4*)(K + cbase);
        const float4* v4 = (const float4*)(V + cbase);
        float4*       o4 = (float4*)(O + cbase);

        float4 cb = ((const float4*)(P + (size_t)chunk * DIM))[h];
        float c_base[4] = {cb.x, cb.y, cb.z, cb.w};

#pragma unroll
        for (int j0 = 0; j0 < CHUNK; j0 += 4) {
            const int row = j0 + g;
            const int idx = row * 16 + h;
            float4 v = v4[idx];
            float4 q = q4[idx];
            float4 k = k4[idx];

            // r = ||Q|| + ||K|| + 1 (16-lane xor-reduce -> all lanes hold it)
            float q2 = q.x*q.x + q.y*q.y + q.z*q.z + q.w*q.w;
            float k2 = k.x*k.x + k.y*k.y + k.z*k.z + k.w*k.w;
#pragma unroll
            for (int m = 1; m < 16; m <<= 1) {
                q2 += __shfl_xor(q2, m);
                k2 += __shfl_xor(k2, m);
            }
            float r = sqrtf(q2) + sqrtf(k2) + 1.0f;

            float sw[4];
            sw[0] = v.x * v.x * fast_sigmoid(v.x);
            sw[1] = v.y * v.y * fast_sigmoid(v.y);
            sw[2] = v.z * v.z * fast_sigmoid(v.z);
            sw[3] = v.w * v.w * fast_sigmoid(v.w);

            // inclusive scan over the 4 row-slot groups (element-wise per d)
#pragma unroll
            for (int i = 0; i < 4; ++i) {
                float tt = __shfl(sw[i], up16);
                sw[i] += (g >= 1) ? tt : 0.f;
            }
#pragma unroll
            for (int i = 0; i < 4; ++i) {
                float tt = __shfl(sw[i], up32);
                sw[i] += (g >= 2) ? tt : 0.f;
            }

            float c_row[4];
#pragma unroll
            for (int i = 0; i < 4; ++i) {
                float tot = __shfl(sw[i], src3);   // full 4-row sum (group 3)
                c_row[i]  = c_base[i] + sw[i];     // c at this group's row
                c_base[i] += tot;                  // carry for next 4 rows
            }

            float c2 = c_row[0]*c_row[0] + c_row[1]*c_row[1]
                     + c_row[2]*c_row[2] + c_row[3]*c_row[3];
#pragma unroll
            for (int m = 1; m < 16; m <<= 1) c2 += __shfl_xor(c2, m);

            float rms_c = fast_rsqrt(c2 * (1.0f / 64.0f) + 1e-5f);
            float s     = rms_c * fast_rcp(r);

            float vv[4] = {v.x, v.y, v.z, v.w};
            float o[4];
#pragma unroll
            for (int i = 0; i < 4; ++i) {
                float m_ = c_row[i] * s;
                o[i] = vv[i] * (1.0f + m_ * fast_sigmoid(m_));
            }

            float o2 = o[0]*o[0] + o[1]*o[1] + o[2]*o[2] + o[3]*o[3];
#pragma unroll
            for (int m = 1; m < 16; m <<= 1) o2 += __shfl_xor(o2, m);

            float rms_o = fast_rsqrt(o2 * (1.0f / 64.0f) + 1e-5f);
            float4 out = {o[0]*rms_o, o[1]*rms_o, o[2]*rms_o, o[3]*rms_o};
            o4[idx] = out;
        }
    }
}

// ---------------------------------------------------------------------------
extern "C" void kernel_launch(void* const* d_in, const int* in_sizes, int n_in,
                              void* d_out, int out_size, void* d_ws, size_t ws_size,
                              hipStream_t stream) {
    const float* Q = (const float*)d_in[0];
    const float* K = (const float*)d_in[1];
    const float* V = (const float*)d_in[2];
    float* O = (float*)d_out;
    float* P = (float*)d_ws;                                   // 2 MB
    int* bar = (int*)((char*)d_ws + (size_t)BH * NCHUNK * DIM * sizeof(float));

    hipMemsetAsync(bar, 0, 4 * sizeof(int), stream);           // re-arm barriers
    k_fused<<<BLOCKS, TPB, 0, stream>>>(Q, K, V, P, O, bar);
}

// Round 6
// 225.146 us; speedup vs baseline: 1.6489x; 1.6489x over previous
//
#include <hip/hip_runtime.h>
#include <math.h>

// Problem constants (B=4, H=16, S=4096, D=64)
#define BH 64
#define SEQ 4096
#define DIM 64
#define CHUNK 32
#define NCHUNK (SEQ / CHUNK)        // 128 chunks per bh
#define NCH_TOT (BH * NCHUNK)       // 8192 chunks total
#define P1_WPB 4                    // k_partials: waves per block
#define CPB 8                       // k_scan: chunks per block (4 waves x 2)
#define SBLOCKS (NCH_TOT / CPB)     // 1024 scan blocks

__device__ __forceinline__ float fast_rcp(float x)  { return __builtin_amdgcn_rcpf(x); }
__device__ __forceinline__ float fast_rsqrt(float x){ return __builtin_amdgcn_rsqf(x); }
__device__ __forceinline__ float fast_sigmoid(float x) {
    return fast_rcp(1.0f + __expf(-x));
}

// 16-lane xor-tree reduce (within the d-group; lane = g*16 + h layout)
__device__ __forceinline__ float red16(float x) {
    x += __shfl_xor(x, 1);
    x += __shfl_xor(x, 2);
    x += __shfl_xor(x, 4);
    x += __shfl_xor(x, 8);
    return x;
}

// ---------------------------------------------------------------------------
// K1: per-chunk swiglu sums from V ONLY (Q,K dropped from this pass; the r
// gate is computed inline in K2 where its loads hide under the scan chain).
// One wave per chunk, 2048 blocks x 256 threads.
// ---------------------------------------------------------------------------
__global__ __launch_bounds__(256) void k_partials(const float* __restrict__ V,
                                                  float* __restrict__ P) {
    const int wave = threadIdx.x >> 6;
    const int lane = threadIdx.x & 63;
    const int g = lane >> 4, h = lane & 15;
    const int chunk = blockIdx.x * P1_WPB + wave;

    const float4* v4 = (const float4*)(V + (size_t)chunk * (CHUNK * DIM));
    float a0 = 0.f, a1 = 0.f, a2 = 0.f, a3 = 0.f;
#pragma unroll
    for (int j0 = 0; j0 < CHUNK; j0 += 4) {
        float4 v = v4[(j0 + g) * 16 + h];
        a0 += v.x * v.x * fast_sigmoid(v.x);
        a1 += v.y * v.y * fast_sigmoid(v.y);
        a2 += v.z * v.z * fast_sigmoid(v.z);
        a3 += v.w * v.w * fast_sigmoid(v.w);
    }
#pragma unroll
    for (int m = 16; m < 64; m <<= 1) {
        a0 += __shfl_xor(a0, m);
        a1 += __shfl_xor(a1, m);
        a2 += __shfl_xor(a2, m);
        a3 += __shfl_xor(a3, m);
    }
    if (g == 0) {
        float4 o = {a0, a1, a2, a3};
        ((float4*)(P + (size_t)chunk * DIM))[h] = o;
    }
}

// ---------------------------------------------------------------------------
// K2 per-row scan step. All indices compile-time within the unrolled caller
// => everything stays in registers (rule: no runtime-indexed arrays).
// Two calls per j0 with independent state give 2x ILP on the shuffle chain.
// ---------------------------------------------------------------------------
__device__ __forceinline__ void scan_step(const float4* __restrict__ q4,
                                          const float4* __restrict__ k4,
                                          const float4* __restrict__ v4,
                                          float4* __restrict__ o4,
                                          float (&cb)[4],
                                          int idx, int g,
                                          int up16, int up32, int src3) {
    float4 v = v4[idx];
    float4 q = q4[idx];
    float4 k = k4[idx];

    // r = ||Q|| + ||K|| + 1  (independent of the scan chain -> free ILP)
    float q2 = red16(q.x*q.x + q.y*q.y + q.z*q.z + q.w*q.w);
    float k2 = red16(k.x*k.x + k.y*k.y + k.z*k.z + k.w*k.w);
    float r  = sqrtf(q2) + sqrtf(k2) + 1.0f;

    float s0 = v.x * v.x * fast_sigmoid(v.x);
    float s1 = v.y * v.y * fast_sigmoid(v.y);
    float s2v = v.z * v.z * fast_sigmoid(v.z);
    float s3 = v.w * v.w * fast_sigmoid(v.w);

    // inclusive scan over the 4 row-slot groups (element-wise per d)
    float t0 = __shfl(s0, up16); s0 += (g >= 1) ? t0 : 0.f;
    float t1 = __shfl(s1, up16); s1 += (g >= 1) ? t1 : 0.f;
    float t2 = __shfl(s2v, up16); s2v += (g >= 1) ? t2 : 0.f;
    float t3 = __shfl(s3, up16); s3 += (g >= 1) ? t3 : 0.f;

    float u0 = __shfl(s0, up32); s0 += (g >= 2) ? u0 : 0.f;
    float u1 = __shfl(s1, up32); s1 += (g >= 2) ? u1 : 0.f;
    float u2 = __shfl(s2v, up32); s2v += (g >= 2) ? u2 : 0.f;
    float u3 = __shfl(s3, up32); s3 += (g >= 2) ? u3 : 0.f;

    float w0 = __shfl(s0, src3);   // full 4-row sums (group 3)
    float w1 = __shfl(s1, src3);
    float w2 = __shfl(s2v, src3);
    float w3 = __shfl(s3, src3);

    float c0 = cb[0] + s0;  cb[0] += w0;
    float c1 = cb[1] + s1;  cb[1] += w1;
    float c2 = cb[2] + s2v; cb[2] += w2;
    float c3 = cb[3] + s3;  cb[3] += w3;

    float cs = red16(c0*c0 + c1*c1 + c2*c2 + c3*c3);
    float rms_c = fast_rsqrt(cs * (1.0f / 64.0f) + 1e-5f);
    float s = rms_c * fast_rcp(r);

    float m0 = c0 * s; float o0 = v.x * (1.0f + m0 * fast_sigmoid(m0));
    float m1 = c1 * s; float o1 = v.y * (1.0f + m1 * fast_sigmoid(m1));
    float m2 = c2 * s; float o2 = v.z * (1.0f + m2 * fast_sigmoid(m2));
    float m3 = c3 * s; float o3 = v.w * (1.0f + m3 * fast_sigmoid(m3));

    float os = red16(o0*o0 + o1*o1 + o2*o2 + o3*o3);
    float rms_o = fast_rsqrt(os * (1.0f / 64.0f) + 1e-5f);
    float4 outv = {o0 * rms_o, o1 * rms_o, o2 * rms_o, o3 * rms_o};
    o4[idx] = outv;
}

// ---------------------------------------------------------------------------
// K2: block b covers global chunks b*8 .. b*8+7 (all in bh = b>>4).
// First: in-block exclusive prefix of the bh's 128 chunk sums (P is L2/L3
// hot, 32 KB/block) -> carries for the block's 8 chunks, no k_prefix kernel.
// Then: each wave scans 2 chunks INTERLEAVED (independent chains -> 2x ILP).
// ---------------------------------------------------------------------------
__global__ __launch_bounds__(256, 4) void k_scan(const float* __restrict__ Q,
                                                 const float* __restrict__ K,
                                                 const float* __restrict__ V,
                                                 const float* __restrict__ P,
                                                 float* __restrict__ O) {
    __shared__ float segsum[4][DIM];
    __shared__ float excl[CPB][DIM];

    const int t    = threadIdx.x;
    const int lane = t & 63;       // doubles as 'd' in the prefix pass
    const int wave = t >> 6;       // doubles as 'seg' in the prefix pass
    const int b    = blockIdx.x;
    const int bib  = b & 15;       // block index within its bh (16 blocks/bh)
    const float* pslab = P + (size_t)(b >> 4) * (NCHUNK * DIM);

    // ---- in-block prefix: seg 'wave' sums chunks [wave*32, wave*32+32) ----
    float run = 0.f, run8 = 0.f, run16 = 0.f, run24 = 0.f;
#pragma unroll
    for (int j = 0; j < 32; ++j) {
        if (j == 8)  run8  = run;
        if (j == 16) run16 = run;
        if (j == 24) run24 = run;
        run += pslab[(wave * 32 + j) * DIM + lane];
    }
    segsum[wave][lane] = run;
    __syncthreads();

    const int seg_t = bib >> 2;          // seg containing this block's window
    const int off   = (bib & 3) * 8;     // window offset within that seg
    if (wave == seg_t) {
        float carry = 0.f;
#pragma unroll
        for (int s = 0; s < 4; ++s)
            if (s < seg_t) carry += segsum[s][lane];
        float ws = carry + (off == 0 ? 0.f :
                            off == 8 ? run8 :
                            off == 16 ? run16 : run24);
#pragma unroll
        for (int i = 0; i < CPB; ++i) {
            excl[i][lane] = ws;
            ws += pslab[(seg_t * 32 + off + i) * DIM + lane];
        }
    }
    __syncthreads();

    // ---- dual-chunk interleaved scan ----
    const int g = lane >> 4, h = lane & 15;
    const int cA = b * CPB + 2 * wave;
    const int cB = cA + 1;
    const size_t baseA = (size_t)cA * (CHUNK * DIM);
    const size_t baseB = (size_t)cB * (CHUNK * DIM);
    const float4* qA = (const float4*)(Q + baseA);
    const float4* kA = (const float4*)(K + baseA);
    const float4* vA = (const float4*)(V + baseA);
    float4*       oA = (float4*)(O + baseA);
    const float4* qB = (const float4*)(Q + baseB);
    const float4* kB = (const float4*)(K + baseB);
    const float4* vB = (const float4*)(V + baseB);
    float4*       oB = (float4*)(O + baseB);

    float4 ea = ((const float4*)excl[2 * wave])[h];
    float4 eb = ((const float4*)excl[2 * wave + 1])[h];
    float cbA[4] = {ea.x, ea.y, ea.z, ea.w};
    float cbB[4] = {eb.x, eb.y, eb.z, eb.w};

    const int up16 = (lane + 48) & 63;   // lane-16 with wrap (masked for g<1)
    const int up32 = (lane + 32) & 63;   // lane-32 with wrap (masked for g<2)
    const int src3 = 48 + h;             // group-3 lane with same h

#pragma unroll
    for (int j0 = 0; j0 < CHUNK; j0 += 4) {
        const int idx = (j0 + g) * 16 + h;
        scan_step(qA, kA, vA, oA, cbA, idx, g, up16, up32, src3);
        scan_step(qB, kB, vB, oB, cbB, idx, g, up16, up32, src3);
    }
}

// ---------------------------------------------------------------------------
extern "C" void kernel_launch(void* const* d_in, const int* in_sizes, int n_in,
                              void* d_out, int out_size, void* d_ws, size_t ws_size,
                              hipStream_t stream) {
    const float* Q = (const float*)d_in[0];
    const float* K = (const float*)d_in[1];
    const float* V = (const float*)d_in[2];
    float* O = (float*)d_out;
    float* P = (float*)d_ws;                       // 8192*64 floats = 2 MB

    k_partials<<<NCH_TOT / P1_WPB, 256, 0, stream>>>(V, P);
    k_scan<<<SBLOCKS, 256, 0, stream>>>(Q, K, V, P, O);
}